// Round 2
// baseline (226.918 us; speedup 1.0000x reference)
//
#include <hip/hip_runtime.h>
#include <stdint.h>

typedef __bf16 bf16_t;
typedef bf16_t bf16x8 __attribute__((ext_vector_type(8)));
typedef float  f32x4  __attribute__((ext_vector_type(4)));
typedef float  f32x2v __attribute__((ext_vector_type(2)));

static constexpr uint32_t PRIME = 2654435761u;
static constexpr uint32_t HMASK = (1u << 17) - 1u;   // HASHMAP_SIZE - 1
static constexpr uint32_t TSIZE = 1u << 17;

// dense mini-grid geometry, levels 0..7 (scale_l = 16*1.5^l, W = ceil(scale)+1)
static constexpr int NDALL  = 136642;   // 17^2+25^2+37^2+55^2+82^2+123^2+184^2+275^2

// features stored as fp8-e4m3 pairs, pre-scaled by 2^13 (|f|<=1e-4 -> +-0.82).
// un-scale 2^-13 is folded into the layer-0 weight fragments.
static constexpr float FSCALE = 8192.0f;        // 2^13
static constexpr float WSCALE = 1.0f / 8192.0f; // 2^-13

__device__ __forceinline__ uint32_t fbits(float f) {
    union { float f; uint32_t u; } v; v.f = f; return v.u;
}
__device__ __forceinline__ float asfloat(uint32_t u) {
    union { uint32_t u; float f; } v; v.u = u; return v.f;
}

// ---- fp8 pair encode/decode (OCP e4m3fn). HW path on gfx950, manual fallback.
__device__ __forceinline__ uint32_t enc8(float v) {   // manual e4m3fn RNE
    const uint32_t s = (fbits(v) >> 24) & 0x80u;
    float m = fabsf(v) * 0x1p-120f;                   // map e4m3 grid onto fp32 bits
    uint32_t u = fbits(m);
    u += 0x7FFFFu + ((u >> 20) & 1u);                 // RNE at bit 20
    return s | ((u >> 20) & 0x7fu);
}
__device__ __forceinline__ uint32_t pack8(float a, float b) {
#if __has_builtin(__builtin_amdgcn_cvt_pk_fp8_f32)
    return (uint32_t)__builtin_amdgcn_cvt_pk_fp8_f32(a, b, 0, false) & 0xffffu;
#else
    return enc8(a) | (enc8(b) << 8);
#endif
}
// unpack one 16-bit fp8-pair from either half of a dword.
// HI must be compile-time (HW word-select is an immediate).
template <bool HI>
__device__ __forceinline__ float2 unpack8w(uint32_t u) {
#if __has_builtin(__builtin_amdgcn_cvt_pk_f32_fp8)
    f32x2v r = __builtin_amdgcn_cvt_pk_f32_fp8((int)u, HI);
    return make_float2(r.x, r.y);
#else
    const uint32_t w = HI ? (u >> 16) : (u & 0xffffu);
    const float f0 = asfloat(((w & 0x80u) << 24) | ((w & 0x7fu) << 20)) * 0x1p120f;
    const float f1 = asfloat(((w & 0x8000u) << 16) | ((w & 0x7f00u) << 12)) * 0x1p120f;
    return make_float2(f0, f1);
#endif
}

// ---- single fused prepass (saves one dispatch):
// blocks [0,512):  repack levels 8..15 of fp32 [T][L][F] -> fp8-pair ushorts,
//                  level-major [l-8][T] (2 MB), LDS-tiled transpose.
// blocks [512, ..): dense mini-grids lv 0..7 as PAIR dwords:
//                  dpair[i] = { point(ix,iy), point(ix+1,iy) } (534 KB) so the
//                  two x-corners of a bilerp come from ONE dword load.
__global__ __launch_bounds__(256)
void prepass_all(const float2* __restrict__ src, uint16_t* __restrict__ tab8,
                 uint32_t* __restrict__ dpair) {
    __shared__ uint16_t ldsT[8 * 257];      // [l8][t_local], +1 pad
    const int tid = threadIdx.x;
    if (blockIdx.x < 512) {
        const int t0 = blockIdx.x * 256;    // 512 blocks x 256 t-entries
#pragma unroll
        for (int k = 0; k < 8; ++k) {
            const int j = k * 256 + tid;    // (t_local, l8): l8 fastest
            const int tl = j >> 3, l8 = j & 7;
            const float2 f = src[((size_t)(t0 + tl) << 4) + 8 + l8];
            ldsT[l8 * 257 + tl] = (uint16_t)pack8(f.x * FSCALE, f.y * FSCALE);
        }
        __syncthreads();
#pragma unroll
        for (int k = 0; k < 8; ++k)
            tab8[((uint32_t)k << 17) + t0 + tid] = ldsT[k * 257 + tid];
    } else {
        const int i = (blockIdx.x - 512) * 256 + tid;
        if (i >= NDALL) return;
        int lvl, W, off;
        if      (i <   289) { lvl = 0; W =  17; off = 0;     }
        else if (i <   914) { lvl = 1; W =  25; off = 289;   }
        else if (i <  2283) { lvl = 2; W =  37; off = 914;   }
        else if (i <  5308) { lvl = 3; W =  55; off = 2283;  }
        else if (i < 12032) { lvl = 4; W =  82; off = 5308;  }
        else if (i < 27161) { lvl = 5; W = 123; off = 12032; }
        else if (i < 61017) { lvl = 6; W = 184; off = 27161; }
        else                { lvl = 7; W = 275; off = 61017; }
        const int li = i - off;
        const uint32_t iy = (uint32_t)(li / W), ix = (uint32_t)(li % W);
        const uint32_t hy = iy * PRIME;
        const uint32_t h0 = ( ix       ^ hy) & HMASK;
        const uint32_t h1 = ((ix + 1u) ^ hy) & HMASK;   // junk for ix=W-1, never read
        const float2 f0 = src[h0 * 16 + lvl];
        const float2 f1 = src[h1 * 16 + lvl];
        dpair[i] = pack8(f0.x * FSCALE, f0.y * FSCALE)
                 | (pack8(f1.x * FSCALE, f1.y * FSCALE) << 16);
    }
}

// One wave = one 16-point tile per iteration. q = lane>>4, n16 = lane&15.
// Lane (q,n16) computes levels 4q..4q+3 of point n16 -> the
// mfma_f32_16x16x32_bf16 A-fragment. Gather routing: q<2 -> dense pair table
// (L1/L2-resident, 534 KB); q>=2 -> hashed fp8 table (2 MB, L2-resident).
//
// SOFTWARE PIPELINE (the point of this version): per level we consume last
// iteration's gather registers into af, then immediately issue the NEXT
// point's gathers into the same slots -> every table load has the whole
// MFMA/transpose chain (~500+ cyc) in flight to hide its L2 latency,
// independent of occupancy. x is prefetched two iterations deep.
//
// LDS transpose tiles are XOR-swizzled (16B block ^= row&7, stride 64):
// writes drop from 8-way bank conflict to <=2-way (free), reads stay
// streaming-equivalent; all offsets fold into hoisted bases + immediates.
__global__ __launch_bounds__(256, 2)
void fused_hash_mlp(const float* __restrict__ xin,
                    const uint16_t* __restrict__ tab8,   // hashed lv8..15, fp8
                    const uint32_t* __restrict__ dpair,  // dense lv0..7, fp8 pairs
                    const float* __restrict__ w0, const float* __restrict__ b0,
                    const float* __restrict__ w1, const float* __restrict__ b1,
                    const float* __restrict__ w2, const float* __restrict__ b2,
                    float* __restrict__ out,
                    int nGroups)
{
    __shared__ __align__(16) bf16_t lds[4 * 16 * 64];    // 8192 B per-wave tiles

    const int tid  = threadIdx.x;
    const int wib  = tid >> 6;      // 0..3
    const int lane = tid & 63;
    const int q    = lane >> 4;
    const int n16  = lane & 15;
    const int m7   = n16 & 7;
    const int mb   = n16 >> 3;

    bf16_t* myLds = &lds[wib * (16 * 64)];

    // ---- weight B-fragments (fp32 -> bf16 once). Bw0 absorbs the 2^-13
    // feature un-scale (A carries feat*2^13).
    bf16x8 Bw0[4], Bw1[2][4], Bw2[2];
#pragma unroll
    for (int t = 0; t < 4; ++t)
#pragma unroll
        for (int j = 0; j < 8; ++j)
            Bw0[t][j] = (bf16_t)(w0[(q * 8 + j) * 64 + t * 16 + n16] * WSCALE);
#pragma unroll
    for (int c = 0; c < 2; ++c)
#pragma unroll
        for (int t = 0; t < 4; ++t)
#pragma unroll
            for (int j = 0; j < 8; ++j)
                Bw1[c][t][j] = (bf16_t)w1[(c * 32 + q * 8 + j) * 64 + t * 16 + n16];
#pragma unroll
    for (int c = 0; c < 2; ++c)
#pragma unroll
        for (int j = 0; j < 8; ++j)
            Bw2[c][j] = (n16 < 3) ? (bf16_t)w2[(c * 32 + q * 8 + j) * 3 + n16]
                                  : (bf16_t)0.0f;

    float bv0[4], bv1[4];
#pragma unroll
    for (int t = 0; t < 4; ++t) {
        bv0[t] = b0[t * 16 + n16];
        bv1[t] = b1[t * 16 + n16];
    }
    const float bv2 = (n16 < 3) ? b2[n16] : 0.0f;

    // scales for levels 4q..4q+3: 16*1.5^l = 3^l * 2^(4-l) is EXACT in fp32,
    // so pos/floor/hash bit-match the fp32 numpy reference.
    const float sb = 16.0f * ((q == 0) ? 1.0f :
                              (q == 1) ? 5.0625f :           // 1.5^4
                              (q == 2) ? 25.62890625f :      // 1.5^8
                                         129.746337890625f); // 1.5^12
    const float sc[4] = { sb, sb * 1.5f, sb * 2.25f, sb * 3.375f };

    // hashed sub-table base for q>=2: level 4q+lv -> [(q-2)*4 + lv] << 17
    const uint32_t l8base = ((uint32_t)((q >= 2 ? q - 2 : 0) * 4)) << 17;

    // ---- swizzled transpose-tile addressing (element units, bf16):
    // write (row=4q+r, col=16t+n16):
    //   idx = row*64 + ((block ^ (row&7))<<3) + (col&7), block = 2t + mb
    // all runtime parts hoisted into wbase[r] (+^32 for t>=2, imm for the rest)
    int wbase[4];
#pragma unroll
    for (int r = 0; r < 4; ++r)
        wbase[r] = (q * 4 + r) * 64 + m7 + ((mb ^ (r & 1)) << 3) + ((q & 1) << 5);
    // read (row=n16, col=c*32+q*8+j): b128 at
    const int rIdx0 = n16 * 64 + (( q      ^ m7) << 3);   // c=0
    const int rIdx1 = n16 * 64 + (((4 + q) ^ m7) << 3);   // c=1

    const int gstride = gridDim.x;
    const int gLast   = nGroups - 1;

    auto ldxy = [&](int gg) -> float2 {
        return ((const float2*)xin)[(gg * 4 + wib) * 16 + n16];
    };

    // pipeline gather registers: q<2 uses [0]=lo-pair,[1]=hi-pair; q>=2 uses all 4
    uint32_t u[4][4] = { {0,0,0,0}, {0,0,0,0}, {0,0,0,0}, {0,0,0,0} };

    auto prefetchLvl = [&](float px, float py, int lv) {
        const float posx = px * sc[lv], posy = py * sc[lv];
        const uint32_t ix = (uint32_t)posx, iy = (uint32_t)posy;
        if (q < 2) {
            const uint32_t Wl = (lv == 0) ? 17u  : (lv == 1) ? 25u
                              : (lv == 2) ? 37u  : 55u;
            const uint32_t Ol = (lv == 0) ? 0u   : (lv == 1) ? 289u
                              : (lv == 2) ? 914u : 2283u;
            const uint32_t Wg = (lv == 0) ? 82u    : (lv == 1) ? 123u
                              : (lv == 2) ? 184u   : 275u;
            const uint32_t Og = (lv == 0) ? 5308u  : (lv == 1) ? 12032u
                              : (lv == 2) ? 27161u : 61017u;
            const uint32_t W = (q == 0) ? Wl : Wg;
            const uint32_t O = (q == 0) ? Ol : Og;
            const uint32_t a = O + iy * W + ix;
            u[lv][0] = dpair[a];            // {(ix,iy),(ix+1,iy)}
            u[lv][1] = dpair[a + W];        // {(ix,iy+1),(ix+1,iy+1)}
        } else {
            const uint32_t hy0 = iy * PRIME, hy1 = hy0 + PRIME;
            const uint32_t base = l8base + ((uint32_t)lv << 17);
            u[lv][0] = tab8[base + (( ix       ^ hy0) & HMASK)];
            u[lv][2] = tab8[base + (((ix + 1u) ^ hy0) & HMASK)];
            u[lv][1] = tab8[base + (( ix       ^ hy1) & HMASK)];
            u[lv][3] = tab8[base + (((ix + 1u) ^ hy1) & HMASK)];
        }
    };

    int g = blockIdx.x;
    if (g > gLast) return;

    // ---- pipeline prologue: x two deep, gathers one deep
    float2 xyA = ldxy(g);
#pragma unroll
    for (int lv = 0; lv < 4; ++lv) prefetchLvl(xyA.x, xyA.y, lv);
    int g1 = g + gstride; if (g1 > gLast) g1 = gLast;
    float2 xyB = ldxy(g1);

    for (; g <= gLast; g += gstride) {
        int gC = g + 2 * gstride; if (gC > gLast) gC = gLast;
        const float2 xyC = ldxy(gC);               // issue x two ahead

        // ---- consume this point's gathers; re-issue next point's per level
        bf16x8 af;
#pragma unroll
        for (int lv = 0; lv < 4; ++lv) {
            const float posx = xyA.x * sc[lv], posy = xyA.y * sc[lv];
            const float frx = posx - floorf(posx), fry = posy - floorf(posy);
            float2 e00, e10, e01, e11;
            if (q < 2) {
                e00 = unpack8w<false>(u[lv][0]); e10 = unpack8w<true>(u[lv][0]);
                e01 = unpack8w<false>(u[lv][1]); e11 = unpack8w<true>(u[lv][1]);
            } else {
                e00 = unpack8w<false>(u[lv][0]); e10 = unpack8w<false>(u[lv][2]);
                e01 = unpack8w<false>(u[lv][1]); e11 = unpack8w<false>(u[lv][3]);
            }
            const float wx1 = frx, wx0 = 1.0f - frx, wy1 = fry, wy0 = 1.0f - fry;
            const float w00 = wx0 * wy0, w10 = wx1 * wy0;
            const float w01 = wx0 * wy1, w11 = wx1 * wy1;
            // bilerp in the scaled (x2^13) domain; Bw0 un-scales.
            const float f0 = w00 * e00.x + w10 * e10.x + w01 * e01.x + w11 * e11.x;
            const float f1 = w00 * e00.y + w10 * e10.y + w01 * e01.y + w11 * e11.y;
            af[2 * lv]     = (bf16_t)f0;
            af[2 * lv + 1] = (bf16_t)f1;
            // old regs dead -> issue next point's level-lv gathers in-place;
            // they stay in flight across the whole MFMA/transpose chain below.
            prefetchLvl(xyB.x, xyB.y, lv);
        }

        // ---- layer 0: [16x32] @ [32x64] + b0, relu ----
        f32x4 c0[4];
#pragma unroll
        for (int t = 0; t < 4; ++t) {
            f32x4 cc = { bv0[t], bv0[t], bv0[t], bv0[t] };
            c0[t] = __builtin_amdgcn_mfma_f32_16x16x32_bf16(af, Bw0[t], cc, 0, 0, 0);
        }

        // C-layout -> A-layout via per-wave private swizzled LDS tile
#pragma unroll
        for (int t = 0; t < 4; ++t)
#pragma unroll
            for (int r = 0; r < 4; ++r) {
                const int idx = ((t < 2) ? wbase[r] : (wbase[r] ^ 32))
                              + ((((t & 1) ^ ((r >> 1) & 1))) << 4);
                myLds[idx] = (bf16_t)fmaxf(c0[t][r], 0.0f);
            }
        bf16x8 A1[2];
        A1[0] = *(const bf16x8*)&myLds[rIdx0];
        A1[1] = *(const bf16x8*)&myLds[rIdx1];

        // ---- layer 1: [16x64] @ [64x64] + b1, relu ----
        f32x4 c1[4];
#pragma unroll
        for (int t = 0; t < 4; ++t) {
            f32x4 cc = { bv1[t], bv1[t], bv1[t], bv1[t] };
            cc    = __builtin_amdgcn_mfma_f32_16x16x32_bf16(A1[0], Bw1[0][t], cc, 0, 0, 0);
            c1[t] = __builtin_amdgcn_mfma_f32_16x16x32_bf16(A1[1], Bw1[1][t], cc, 0, 0, 0);
        }

#pragma unroll
        for (int t = 0; t < 4; ++t)
#pragma unroll
            for (int r = 0; r < 4; ++r) {
                const int idx = ((t < 2) ? wbase[r] : (wbase[r] ^ 32))
                              + ((((t & 1) ^ ((r >> 1) & 1))) << 4);
                myLds[idx] = (bf16_t)fmaxf(c1[t][r], 0.0f);
            }
        bf16x8 A2[2];
        A2[0] = *(const bf16x8*)&myLds[rIdx0];
        A2[1] = *(const bf16x8*)&myLds[rIdx1];

        // ---- layer 2: [16x64] @ [64x3 padded to 16] + b2 (no relu) ----
        f32x4 co = { bv2, bv2, bv2, bv2 };
        co = __builtin_amdgcn_mfma_f32_16x16x32_bf16(A2[0], Bw2[0], co, 0, 0, 0);
        co = __builtin_amdgcn_mfma_f32_16x16x32_bf16(A2[1], Bw2[1], co, 0, 0, 0);

        const int tile = g * 4 + wib;
        if (n16 < 3) {
#pragma unroll
            for (int r = 0; r < 4; ++r)
                out[(size_t)(tile * 16 + q * 4 + r) * 3 + n16] = co[r];
        }

        // ---- rotate pipeline
        xyA = xyB; xyB = xyC;
    }
}

// ---- fallback (R2 known-good): direct fp32 gather, used only if ws too small
__global__ __launch_bounds__(256)
void fused_hash_mlp_fp32(const float* __restrict__ xin,
                         const float* __restrict__ enc,
                         const float* __restrict__ w0, const float* __restrict__ b0,
                         const float* __restrict__ w1, const float* __restrict__ b1,
                         const float* __restrict__ w2, const float* __restrict__ b2,
                         float* __restrict__ out,
                         int nGroups)
{
    __shared__ __align__(16) bf16_t lds[4 * 16 * 80];
    const int tid  = threadIdx.x;
    const int wib  = tid >> 6;
    const int lane = tid & 63;
    const int q    = lane >> 4;
    const int n16  = lane & 15;
    bf16_t* myLds = &lds[wib * (16 * 80)];

    bf16x8 Bw0[4], Bw1[2][4], Bw2[2];
#pragma unroll
    for (int t = 0; t < 4; ++t)
#pragma unroll
        for (int j = 0; j < 8; ++j)
            Bw0[t][j] = (bf16_t)w0[(q * 8 + j) * 64 + t * 16 + n16];
#pragma unroll
    for (int c = 0; c < 2; ++c)
#pragma unroll
        for (int t = 0; t < 4; ++t)
#pragma unroll
            for (int j = 0; j < 8; ++j)
                Bw1[c][t][j] = (bf16_t)w1[(c * 32 + q * 8 + j) * 64 + t * 16 + n16];
#pragma unroll
    for (int c = 0; c < 2; ++c)
#pragma unroll
        for (int j = 0; j < 8; ++j)
            Bw2[c][j] = (n16 < 3) ? (bf16_t)w2[(c * 32 + q * 8 + j) * 3 + n16]
                                  : (bf16_t)0.0f;

    float bv0[4], bv1[4];
#pragma unroll
    for (int t = 0; t < 4; ++t) { bv0[t] = b0[t * 16 + n16]; bv1[t] = b1[t * 16 + n16]; }
    const float bv2 = (n16 < 3) ? b2[n16] : 0.0f;

    const float sb = 16.0f * ((q == 0) ? 1.0f : (q == 1) ? 5.0625f :
                              (q == 2) ? 25.62890625f : 129.746337890625f);
    const float sc[4] = { sb, sb * 1.5f, sb * 2.25f, sb * 3.375f };
    const char* encB = (const char*)enc;
    const uint32_t lvBase = (uint32_t)q * 32u;

    for (int g = blockIdx.x; g < nGroups; g += gridDim.x) {
        const int tile = g * 4 + wib;
        const int p = tile * 16 + n16;
        const float2 xy = ((const float2*)xin)[p];
        const float px = xy.x, py = xy.y;

        bf16x8 af;
#pragma unroll
        for (int lv = 0; lv < 4; ++lv) {
            const float posx = px * sc[lv], posy = py * sc[lv];
            const float fx = floorf(posx), fy = floorf(posy);
            const float frx = posx - fx,  fry = posy - fy;
            const uint32_t ix = (uint32_t)fx, iy = (uint32_t)fy;
            const uint32_t hy0 = iy * PRIME, hy1 = hy0 + PRIME;
            const uint32_t i00 = ( ix       ^ hy0) & HMASK;
            const uint32_t i10 = ((ix + 1u) ^ hy0) & HMASK;
            const uint32_t i01 = ( ix       ^ hy1) & HMASK;
            const uint32_t i11 = ((ix + 1u) ^ hy1) & HMASK;
            const uint32_t off = lvBase + (uint32_t)lv * 8u;
            const float2 e00 = *(const float2*)(encB + (i00 * 128u + off));
            const float2 e10 = *(const float2*)(encB + (i10 * 128u + off));
            const float2 e01 = *(const float2*)(encB + (i01 * 128u + off));
            const float2 e11 = *(const float2*)(encB + (i11 * 128u + off));
            const float wx1 = frx, wx0 = 1.0f - frx, wy1 = fry, wy0 = 1.0f - fry;
            const float w00 = wx0 * wy0, w10 = wx1 * wy0, w01 = wx0 * wy1, w11 = wx1 * wy1;
            af[2 * lv]     = (bf16_t)(w00 * e00.x + w10 * e10.x + w01 * e01.x + w11 * e11.x);
            af[2 * lv + 1] = (bf16_t)(w00 * e00.y + w10 * e10.y + w01 * e01.y + w11 * e11.y);
        }

        f32x4 c0[4];
#pragma unroll
        for (int t = 0; t < 4; ++t) {
            f32x4 cc = { bv0[t], bv0[t], bv0[t], bv0[t] };
            c0[t] = __builtin_amdgcn_mfma_f32_16x16x32_bf16(af, Bw0[t], cc, 0, 0, 0);
        }
        __syncthreads();
#pragma unroll
        for (int t = 0; t < 4; ++t)
#pragma unroll
            for (int r = 0; r < 4; ++r)
                myLds[(q * 4 + r) * 80 + t * 16 + n16] = (bf16_t)fmaxf(c0[t][r], 0.0f);
        __syncthreads();
        bf16x8 A1[2];
#pragma unroll
        for (int c = 0; c < 2; ++c)
            A1[c] = *(const bf16x8*)&myLds[n16 * 80 + c * 32 + q * 8];

        f32x4 c1[4];
#pragma unroll
        for (int t = 0; t < 4; ++t) {
            f32x4 cc = { bv1[t], bv1[t], bv1[t], bv1[t] };
            cc    = __builtin_amdgcn_mfma_f32_16x16x32_bf16(A1[0], Bw1[0][t], cc, 0, 0, 0);
            c1[t] = __builtin_amdgcn_mfma_f32_16x16x32_bf16(A1[1], Bw1[1][t], cc, 0, 0, 0);
        }
        __syncthreads();
#pragma unroll
        for (int t = 0; t < 4; ++t)
#pragma unroll
            for (int r = 0; r < 4; ++r)
                myLds[(q * 4 + r) * 80 + t * 16 + n16] = (bf16_t)fmaxf(c1[t][r], 0.0f);
        __syncthreads();
        bf16x8 A2[2];
#pragma unroll
        for (int c = 0; c < 2; ++c)
            A2[c] = *(const bf16x8*)&myLds[n16 * 80 + c * 32 + q * 8];

        f32x4 co = { bv2, bv2, bv2, bv2 };
        co = __builtin_amdgcn_mfma_f32_16x16x32_bf16(A2[0], Bw2[0], co, 0, 0, 0);
        co = __builtin_amdgcn_mfma_f32_16x16x32_bf16(A2[1], Bw2[1], co, 0, 0, 0);
        if (n16 < 3) {
#pragma unroll
            for (int r = 0; r < 4; ++r)
                out[(size_t)(tile * 16 + q * 4 + r) * 3 + n16] = co[r];
        }
    }
}

extern "C" void kernel_launch(void* const* d_in, const int* in_sizes, int n_in,
                              void* d_out, int out_size, void* d_ws, size_t ws_size,
                              hipStream_t stream) {
    const float* x  = (const float*)d_in[0];
    const float* en = (const float*)d_in[1];
    const float* w0 = (const float*)d_in[2];
    const float* b0 = (const float*)d_in[3];
    const float* w1 = (const float*)d_in[4];
    const float* b1 = (const float*)d_in[5];
    const float* w2 = (const float*)d_in[6];
    const float* b2 = (const float*)d_in[7];
    float* out = (float*)d_out;

    const int N = in_sizes[0] / 2;      // 2^20 points
    const int nTiles = N / 16;          // 65536
    const int nGroups = nTiles / 4;     // 16384 (4 waves/block)

    const size_t tabBytes = (size_t)TSIZE * 8 * 2;               // 2 MB
    const size_t wsNeeded = tabBytes + (size_t)NDALL * 4;        // ~2.64 MB
    if (ws_size >= wsNeeded) {
        uint16_t* tab8  = (uint16_t*)d_ws;
        uint32_t* dpair = (uint32_t*)((char*)d_ws + tabBytes);
        const int preBlocks = 512 + (NDALL + 255) / 256;         // 1046
        prepass_all<<<preBlocks, 256, 0, stream>>>((const float2*)en, tab8, dpair);
        int blocks = 2048;
        if (blocks > nGroups) blocks = nGroups;
        fused_hash_mlp<<<blocks, 256, 0, stream>>>(x, tab8, dpair,
                                                   w0, b0, w1, b1, w2, b2, out, nGroups);
    } else {
        int blocks = 2048;
        if (blocks > nGroups) blocks = nGroups;
        fused_hash_mlp_fp32<<<blocks, 256, 0, stream>>>(x, en, w0, b0, w1, b1, w2, b2, out, nGroups);
    }
}

// Round 3
// 215.772 us; speedup vs baseline: 1.0517x; 1.0517x over previous
//
#include <hip/hip_runtime.h>
#include <stdint.h>

typedef __bf16 bf16_t;
typedef bf16_t bf16x8 __attribute__((ext_vector_type(8)));
typedef float  f32x4  __attribute__((ext_vector_type(4)));
typedef float  f32x2v __attribute__((ext_vector_type(2)));

static constexpr uint32_t PRIME = 2654435761u;
static constexpr uint32_t HMASK = (1u << 17) - 1u;   // HASHMAP_SIZE - 1
static constexpr uint32_t TSIZE = 1u << 17;

// dense mini-grid geometry, levels 0..7 (scale_l = 16*1.5^l, W = ceil(scale)+1)
static constexpr int NDALL  = 136642;   // 17^2+25^2+37^2+55^2+82^2+123^2+184^2+275^2

// features stored as fp8-e4m3 pairs, pre-scaled by 2^13 (|f|<=1e-4 -> +-0.82).
// un-scale 2^-13 is folded into the layer-0 weight fragments.
static constexpr float FSCALE = 8192.0f;        // 2^13
static constexpr float WSCALE = 1.0f / 8192.0f; // 2^-13

__device__ __forceinline__ uint32_t fbits(float f) {
    union { float f; uint32_t u; } v; v.f = f; return v.u;
}
__device__ __forceinline__ float asfloat(uint32_t u) {
    union { uint32_t u; float f; } v; v.u = u; return v.f;
}

// ---- fp8 pair encode/decode (OCP e4m3fn). HW path on gfx950, manual fallback.
__device__ __forceinline__ uint32_t enc8(float v) {   // manual e4m3fn RNE
    const uint32_t s = (fbits(v) >> 24) & 0x80u;
    float m = fabsf(v) * 0x1p-120f;                   // map e4m3 grid onto fp32 bits
    uint32_t u = fbits(m);
    u += 0x7FFFFu + ((u >> 20) & 1u);                 // RNE at bit 20
    return s | ((u >> 20) & 0x7fu);
}
__device__ __forceinline__ uint32_t pack8(float a, float b) {
#if __has_builtin(__builtin_amdgcn_cvt_pk_fp8_f32)
    return (uint32_t)__builtin_amdgcn_cvt_pk_fp8_f32(a, b, 0, false) & 0xffffu;
#else
    return enc8(a) | (enc8(b) << 8);
#endif
}
// unpack one 16-bit fp8-pair from either half of a dword.
// HI must be compile-time (HW word-select is an immediate).
template <bool HI>
__device__ __forceinline__ float2 unpack8w(uint32_t u) {
#if __has_builtin(__builtin_amdgcn_cvt_pk_f32_fp8)
    f32x2v r = __builtin_amdgcn_cvt_pk_f32_fp8((int)u, HI);
    return make_float2(r.x, r.y);
#else
    const uint32_t w = HI ? (u >> 16) : (u & 0xffffu);
    const float f0 = asfloat(((w & 0x80u) << 24) | ((w & 0x7fu) << 20)) * 0x1p120f;
    const float f1 = asfloat(((w & 0x8000u) << 16) | ((w & 0x7f00u) << 12)) * 0x1p120f;
    return make_float2(f0, f1);
#endif
}

// ---- single fused prepass:
// blocks [0,512):  repack levels 8..15 of fp32 [T][L][F] -> fp8-pair ushorts,
//                  level-major [l-8][T] (2 MB), LDS-tiled transpose.
// blocks [512, ..): dense mini-grids lv 0..7 as PAIR dwords:
//                  dpair[i] = { point(ix,iy), point(ix+1,iy) } (534 KB) so the
//                  two x-corners of a bilerp come from ONE dword load.
__global__ __launch_bounds__(256)
void prepass_all(const float2* __restrict__ src, uint16_t* __restrict__ tab8,
                 uint32_t* __restrict__ dpair) {
    __shared__ uint16_t ldsT[8 * 257];      // [l8][t_local], +1 pad
    const int tid = threadIdx.x;
    if (blockIdx.x < 512) {
        const int t0 = blockIdx.x * 256;    // 512 blocks x 256 t-entries
#pragma unroll
        for (int k = 0; k < 8; ++k) {
            const int j = k * 256 + tid;    // (t_local, l8): l8 fastest
            const int tl = j >> 3, l8 = j & 7;
            const float2 f = src[((size_t)(t0 + tl) << 4) + 8 + l8];
            ldsT[l8 * 257 + tl] = (uint16_t)pack8(f.x * FSCALE, f.y * FSCALE);
        }
        __syncthreads();
#pragma unroll
        for (int k = 0; k < 8; ++k)
            tab8[((uint32_t)k << 17) + t0 + tid] = ldsT[k * 257 + tid];
    } else {
        const int i = (blockIdx.x - 512) * 256 + tid;
        if (i >= NDALL) return;
        int lvl, W, off;
        if      (i <   289) { lvl = 0; W =  17; off = 0;     }
        else if (i <   914) { lvl = 1; W =  25; off = 289;   }
        else if (i <  2283) { lvl = 2; W =  37; off = 914;   }
        else if (i <  5308) { lvl = 3; W =  55; off = 2283;  }
        else if (i < 12032) { lvl = 4; W =  82; off = 5308;  }
        else if (i < 27161) { lvl = 5; W = 123; off = 12032; }
        else if (i < 61017) { lvl = 6; W = 184; off = 27161; }
        else                { lvl = 7; W = 275; off = 61017; }
        const int li = i - off;
        const uint32_t iy = (uint32_t)(li / W), ix = (uint32_t)(li % W);
        const uint32_t hy = iy * PRIME;
        const uint32_t h0 = ( ix       ^ hy) & HMASK;
        const uint32_t h1 = ((ix + 1u) ^ hy) & HMASK;   // junk for ix=W-1, never read
        const float2 f0 = src[h0 * 16 + lvl];
        const float2 f1 = src[h1 * 16 + lvl];
        dpair[i] = pack8(f0.x * FSCALE, f0.y * FSCALE)
                 | (pack8(f1.x * FSCALE, f1.y * FSCALE) << 16);
    }
}

// One wave = one 16-point tile per iteration. q = lane>>4, n16 = lane&15.
// Lane (q,n16) computes levels 4q..4q+3 of point n16 -> the
// mfma_f32_16x16x32_bf16 A-fragment. Gather routing: q<2 -> dense pair table
// (L1/L2-resident, 534 KB); q>=2 -> hashed fp8 table (2 MB, L2-resident).
//
// R2 STRUCTURE (rotation reverted): gathers are issued and consumed WITHIN
// the iteration, but phase-split: all 16 loads issued back-to-back before the
// first unpack, so one vmcnt wait covers them all. Only the x-load is
// pipelined (1-deep, one float2 reg) to take ~900cyc HBM latency off the
// serial path. Transpose tiles stay XOR-swizzled (R2-verified: conflicts=0).
__global__ __launch_bounds__(256, 2)
void fused_hash_mlp(const float* __restrict__ xin,
                    const uint16_t* __restrict__ tab8,   // hashed lv8..15, fp8
                    const uint32_t* __restrict__ dpair,  // dense lv0..7, fp8 pairs
                    const float* __restrict__ w0, const float* __restrict__ b0,
                    const float* __restrict__ w1, const float* __restrict__ b1,
                    const float* __restrict__ w2, const float* __restrict__ b2,
                    float* __restrict__ out,
                    int nGroups)
{
    __shared__ __align__(16) bf16_t lds[4 * 16 * 64];    // 8192 B per-wave tiles

    const int tid  = threadIdx.x;
    const int wib  = tid >> 6;      // 0..3
    const int lane = tid & 63;
    const int q    = lane >> 4;
    const int n16  = lane & 15;
    const int m7   = n16 & 7;
    const int mb   = n16 >> 3;

    bf16_t* myLds = &lds[wib * (16 * 64)];

    // ---- weight B-fragments (fp32 -> bf16 once). Bw0 absorbs the 2^-13
    // feature un-scale (A carries feat*2^13).
    bf16x8 Bw0[4], Bw1[2][4], Bw2[2];
#pragma unroll
    for (int t = 0; t < 4; ++t)
#pragma unroll
        for (int j = 0; j < 8; ++j)
            Bw0[t][j] = (bf16_t)(w0[(q * 8 + j) * 64 + t * 16 + n16] * WSCALE);
#pragma unroll
    for (int c = 0; c < 2; ++c)
#pragma unroll
        for (int t = 0; t < 4; ++t)
#pragma unroll
            for (int j = 0; j < 8; ++j)
                Bw1[c][t][j] = (bf16_t)w1[(c * 32 + q * 8 + j) * 64 + t * 16 + n16];
#pragma unroll
    for (int c = 0; c < 2; ++c)
#pragma unroll
        for (int j = 0; j < 8; ++j)
            Bw2[c][j] = (n16 < 3) ? (bf16_t)w2[(c * 32 + q * 8 + j) * 3 + n16]
                                  : (bf16_t)0.0f;

    float bv0[4], bv1[4];
#pragma unroll
    for (int t = 0; t < 4; ++t) {
        bv0[t] = b0[t * 16 + n16];
        bv1[t] = b1[t * 16 + n16];
    }
    const float bv2 = (n16 < 3) ? b2[n16] : 0.0f;

    // scales for levels 4q..4q+3: 16*1.5^l = 3^l * 2^(4-l) is EXACT in fp32,
    // so pos/floor/hash bit-match the fp32 numpy reference.
    const float sb = 16.0f * ((q == 0) ? 1.0f :
                              (q == 1) ? 5.0625f :           // 1.5^4
                              (q == 2) ? 25.62890625f :      // 1.5^8
                                         129.746337890625f); // 1.5^12
    const float sc[4] = { sb, sb * 1.5f, sb * 2.25f, sb * 3.375f };

    // hashed sub-table base for q>=2: level 4q+lv -> [(q-2)*4 + lv] << 17
    const uint32_t l8base = ((uint32_t)((q >= 2 ? q - 2 : 0) * 4)) << 17;

    // ---- swizzled transpose-tile addressing (element units, bf16):
    // write (row=4q+r, col=16t+n16):
    //   idx = row*64 + ((block ^ (row&7))<<3) + (col&7), block = 2t + mb
    // all runtime parts hoisted into wbase[r] (+^32 for t>=2, imm for the rest)
    int wbase[4];
#pragma unroll
    for (int r = 0; r < 4; ++r)
        wbase[r] = (q * 4 + r) * 64 + m7 + ((mb ^ (r & 1)) << 3) + ((q & 1) << 5);
    // read (row=n16, col=c*32+q*8+j): b128 at
    const int rIdx0 = n16 * 64 + (( q      ^ m7) << 3);   // c=0
    const int rIdx1 = n16 * 64 + (((4 + q) ^ m7) << 3);   // c=1

    const int gstride = gridDim.x;
    const int gLast   = nGroups - 1;

    auto ldxy = [&](int gg) -> float2 {
        return ((const float2*)xin)[(gg * 4 + wib) * 16 + n16];
    };

    int g = blockIdx.x;
    if (g > gLast) return;

    float2 xyA = ldxy(g);                       // prologue: first x

    for (; g <= gLast; g += gstride) {
        int gN = g + gstride; if (gN > gLast) gN = gLast;
        const float2 xyN = ldxy(gN);            // 1-deep x prefetch (HBM)

        // ---- phase 1: all address math + issue ALL 16 gathers back-to-back
        uint32_t u[4][4];
        float frx[4], fry[4];
#pragma unroll
        for (int lv = 0; lv < 4; ++lv) {
            const float posx = xyA.x * sc[lv], posy = xyA.y * sc[lv];
            const float fx = floorf(posx), fy = floorf(posy);
            frx[lv] = posx - fx; fry[lv] = posy - fy;
            const uint32_t ix = (uint32_t)fx, iy = (uint32_t)fy;
            if (q < 2) {
                const uint32_t Wl = (lv == 0) ? 17u  : (lv == 1) ? 25u
                                  : (lv == 2) ? 37u  : 55u;
                const uint32_t Ol = (lv == 0) ? 0u   : (lv == 1) ? 289u
                                  : (lv == 2) ? 914u : 2283u;
                const uint32_t Wg = (lv == 0) ? 82u    : (lv == 1) ? 123u
                                  : (lv == 2) ? 184u   : 275u;
                const uint32_t Og = (lv == 0) ? 5308u  : (lv == 1) ? 12032u
                                  : (lv == 2) ? 27161u : 61017u;
                const uint32_t W = (q == 0) ? Wl : Wg;
                const uint32_t O = (q == 0) ? Ol : Og;
                const uint32_t a = O + iy * W + ix;
                u[lv][0] = dpair[a];            // {(ix,iy),(ix+1,iy)}
                u[lv][1] = dpair[a + W];        // {(ix,iy+1),(ix+1,iy+1)}
                u[lv][2] = 0; u[lv][3] = 0;
            } else {
                const uint32_t hy0 = iy * PRIME, hy1 = hy0 + PRIME;
                const uint32_t base = l8base + ((uint32_t)lv << 17);
                u[lv][0] = tab8[base + (( ix       ^ hy0) & HMASK)];
                u[lv][2] = tab8[base + (((ix + 1u) ^ hy0) & HMASK)];
                u[lv][1] = tab8[base + (( ix       ^ hy1) & HMASK)];
                u[lv][3] = tab8[base + (((ix + 1u) ^ hy1) & HMASK)];
            }
        }

        // ---- phase 2: unpack + bilerp -> A-fragment
        bf16x8 af;
#pragma unroll
        for (int lv = 0; lv < 4; ++lv) {
            float2 e00, e10, e01, e11;
            if (q < 2) {
                e00 = unpack8w<false>(u[lv][0]); e10 = unpack8w<true>(u[lv][0]);
                e01 = unpack8w<false>(u[lv][1]); e11 = unpack8w<true>(u[lv][1]);
            } else {
                e00 = unpack8w<false>(u[lv][0]); e10 = unpack8w<false>(u[lv][2]);
                e01 = unpack8w<false>(u[lv][1]); e11 = unpack8w<false>(u[lv][3]);
            }
            const float wx1 = frx[lv], wx0 = 1.0f - frx[lv];
            const float wy1 = fry[lv], wy0 = 1.0f - fry[lv];
            const float w00 = wx0 * wy0, w10 = wx1 * wy0;
            const float w01 = wx0 * wy1, w11 = wx1 * wy1;
            // bilerp in the scaled (x2^13) domain; Bw0 un-scales.
            const float f0 = w00 * e00.x + w10 * e10.x + w01 * e01.x + w11 * e11.x;
            const float f1 = w00 * e00.y + w10 * e10.y + w01 * e01.y + w11 * e11.y;
            af[2 * lv]     = (bf16_t)f0;
            af[2 * lv + 1] = (bf16_t)f1;
        }

        // ---- layer 0: [16x32] @ [32x64] + b0, relu ----
        f32x4 c0[4];
#pragma unroll
        for (int t = 0; t < 4; ++t) {
            f32x4 cc = { bv0[t], bv0[t], bv0[t], bv0[t] };
            c0[t] = __builtin_amdgcn_mfma_f32_16x16x32_bf16(af, Bw0[t], cc, 0, 0, 0);
        }

        // C-layout -> A-layout via per-wave private swizzled LDS tile
#pragma unroll
        for (int t = 0; t < 4; ++t)
#pragma unroll
            for (int r = 0; r < 4; ++r) {
                const int idx = ((t < 2) ? wbase[r] : (wbase[r] ^ 32))
                              + ((((t & 1) ^ ((r >> 1) & 1))) << 4);
                myLds[idx] = (bf16_t)fmaxf(c0[t][r], 0.0f);
            }
        bf16x8 A1[2];
        A1[0] = *(const bf16x8*)&myLds[rIdx0];
        A1[1] = *(const bf16x8*)&myLds[rIdx1];

        // ---- layer 1: [16x64] @ [64x64] + b1, relu ----
        f32x4 c1[4];
#pragma unroll
        for (int t = 0; t < 4; ++t) {
            f32x4 cc = { bv1[t], bv1[t], bv1[t], bv1[t] };
            cc    = __builtin_amdgcn_mfma_f32_16x16x32_bf16(A1[0], Bw1[0][t], cc, 0, 0, 0);
            c1[t] = __builtin_amdgcn_mfma_f32_16x16x32_bf16(A1[1], Bw1[1][t], cc, 0, 0, 0);
        }

#pragma unroll
        for (int t = 0; t < 4; ++t)
#pragma unroll
            for (int r = 0; r < 4; ++r) {
                const int idx = ((t < 2) ? wbase[r] : (wbase[r] ^ 32))
                              + ((((t & 1) ^ ((r >> 1) & 1))) << 4);
                myLds[idx] = (bf16_t)fmaxf(c1[t][r], 0.0f);
            }
        bf16x8 A2[2];
        A2[0] = *(const bf16x8*)&myLds[rIdx0];
        A2[1] = *(const bf16x8*)&myLds[rIdx1];

        // ---- layer 2: [16x64] @ [64x3 padded to 16] + b2 (no relu) ----
        f32x4 co = { bv2, bv2, bv2, bv2 };
        co = __builtin_amdgcn_mfma_f32_16x16x32_bf16(A2[0], Bw2[0], co, 0, 0, 0);
        co = __builtin_amdgcn_mfma_f32_16x16x32_bf16(A2[1], Bw2[1], co, 0, 0, 0);

        const int tile = g * 4 + wib;
        if (n16 < 3) {
#pragma unroll
            for (int r = 0; r < 4; ++r)
                out[(size_t)(tile * 16 + q * 4 + r) * 3 + n16] = co[r];
        }

        xyA = xyN;      // rotate the (only) pipelined value
    }
}

// ---- fallback (R2 known-good): direct fp32 gather, used only if ws too small
__global__ __launch_bounds__(256)
void fused_hash_mlp_fp32(const float* __restrict__ xin,
                         const float* __restrict__ enc,
                         const float* __restrict__ w0, const float* __restrict__ b0,
                         const float* __restrict__ w1, const float* __restrict__ b1,
                         const float* __restrict__ w2, const float* __restrict__ b2,
                         float* __restrict__ out,
                         int nGroups)
{
    __shared__ __align__(16) bf16_t lds[4 * 16 * 80];
    const int tid  = threadIdx.x;
    const int wib  = tid >> 6;
    const int lane = tid & 63;
    const int q    = lane >> 4;
    const int n16  = lane & 15;
    bf16_t* myLds = &lds[wib * (16 * 80)];

    bf16x8 Bw0[4], Bw1[2][4], Bw2[2];
#pragma unroll
    for (int t = 0; t < 4; ++t)
#pragma unroll
        for (int j = 0; j < 8; ++j)
            Bw0[t][j] = (bf16_t)w0[(q * 8 + j) * 64 + t * 16 + n16];
#pragma unroll
    for (int c = 0; c < 2; ++c)
#pragma unroll
        for (int t = 0; t < 4; ++t)
#pragma unroll
            for (int j = 0; j < 8; ++j)
                Bw1[c][t][j] = (bf16_t)w1[(c * 32 + q * 8 + j) * 64 + t * 16 + n16];
#pragma unroll
    for (int c = 0; c < 2; ++c)
#pragma unroll
        for (int j = 0; j < 8; ++j)
            Bw2[c][j] = (n16 < 3) ? (bf16_t)w2[(c * 32 + q * 8 + j) * 3 + n16]
                                  : (bf16_t)0.0f;

    float bv0[4], bv1[4];
#pragma unroll
    for (int t = 0; t < 4; ++t) { bv0[t] = b0[t * 16 + n16]; bv1[t] = b1[t * 16 + n16]; }
    const float bv2 = (n16 < 3) ? b2[n16] : 0.0f;

    const float sb = 16.0f * ((q == 0) ? 1.0f : (q == 1) ? 5.0625f :
                              (q == 2) ? 25.62890625f : 129.746337890625f);
    const float sc[4] = { sb, sb * 1.5f, sb * 2.25f, sb * 3.375f };
    const char* encB = (const char*)enc;
    const uint32_t lvBase = (uint32_t)q * 32u;

    for (int g = blockIdx.x; g < nGroups; g += gridDim.x) {
        const int tile = g * 4 + wib;
        const int p = tile * 16 + n16;
        const float2 xy = ((const float2*)xin)[p];
        const float px = xy.x, py = xy.y;

        bf16x8 af;
#pragma unroll
        for (int lv = 0; lv < 4; ++lv) {
            const float posx = px * sc[lv], posy = py * sc[lv];
            const float fx = floorf(posx), fy = floorf(posy);
            const float frx = posx - fx,  fry = posy - fy;
            const uint32_t ix = (uint32_t)fx, iy = (uint32_t)fy;
            const uint32_t hy0 = iy * PRIME, hy1 = hy0 + PRIME;
            const uint32_t i00 = ( ix       ^ hy0) & HMASK;
            const uint32_t i10 = ((ix + 1u) ^ hy0) & HMASK;
            const uint32_t i01 = ( ix       ^ hy1) & HMASK;
            const uint32_t i11 = ((ix + 1u) ^ hy1) & HMASK;
            const uint32_t off = lvBase + (uint32_t)lv * 8u;
            const float2 e00 = *(const float2*)(encB + (i00 * 128u + off));
            const float2 e10 = *(const float2*)(encB + (i10 * 128u + off));
            const float2 e01 = *(const float2*)(encB + (i01 * 128u + off));
            const float2 e11 = *(const float2*)(encB + (i11 * 128u + off));
            const float wx1 = frx, wx0 = 1.0f - frx, wy1 = fry, wy0 = 1.0f - fry;
            const float w00 = wx0 * wy0, w10 = wx1 * wy0, w01 = wx0 * wy1, w11 = wx1 * wy1;
            af[2 * lv]     = (bf16_t)(w00 * e00.x + w10 * e10.x + w01 * e01.x + w11 * e11.x);
            af[2 * lv + 1] = (bf16_t)(w00 * e00.y + w10 * e10.y + w01 * e01.y + w11 * e11.y);
        }

        f32x4 c0[4];
#pragma unroll
        for (int t = 0; t < 4; ++t) {
            f32x4 cc = { bv0[t], bv0[t], bv0[t], bv0[t] };
            c0[t] = __builtin_amdgcn_mfma_f32_16x16x32_bf16(af, Bw0[t], cc, 0, 0, 0);
        }
        __syncthreads();
#pragma unroll
        for (int t = 0; t < 4; ++t)
#pragma unroll
            for (int r = 0; r < 4; ++r)
                myLds[(q * 4 + r) * 80 + t * 16 + n16] = (bf16_t)fmaxf(c0[t][r], 0.0f);
        __syncthreads();
        bf16x8 A1[2];
#pragma unroll
        for (int c = 0; c < 2; ++c)
            A1[c] = *(const bf16x8*)&myLds[n16 * 80 + c * 32 + q * 8];

        f32x4 c1[4];
#pragma unroll
        for (int t = 0; t < 4; ++t) {
            f32x4 cc = { bv1[t], bv1[t], bv1[t], bv1[t] };
            cc    = __builtin_amdgcn_mfma_f32_16x16x32_bf16(A1[0], Bw1[0][t], cc, 0, 0, 0);
            c1[t] = __builtin_amdgcn_mfma_f32_16x16x32_bf16(A1[1], Bw1[1][t], cc, 0, 0, 0);
        }
        __syncthreads();
#pragma unroll
        for (int t = 0; t < 4; ++t)
#pragma unroll
            for (int r = 0; r < 4; ++r)
                myLds[(q * 4 + r) * 80 + t * 16 + n16] = (bf16_t)fmaxf(c1[t][r], 0.0f);
        __syncthreads();
        bf16x8 A2[2];
#pragma unroll
        for (int c = 0; c < 2; ++c)
            A2[c] = *(const bf16x8*)&myLds[n16 * 80 + c * 32 + q * 8];

        f32x4 co = { bv2, bv2, bv2, bv2 };
        co = __builtin_amdgcn_mfma_f32_16x16x32_bf16(A2[0], Bw2[0], co, 0, 0, 0);
        co = __builtin_amdgcn_mfma_f32_16x16x32_bf16(A2[1], Bw2[1], co, 0, 0, 0);
        if (n16 < 3) {
#pragma unroll
            for (int r = 0; r < 4; ++r)
                out[(size_t)(tile * 16 + q * 4 + r) * 3 + n16] = co[r];
        }
    }
}

extern "C" void kernel_launch(void* const* d_in, const int* in_sizes, int n_in,
                              void* d_out, int out_size, void* d_ws, size_t ws_size,
                              hipStream_t stream) {
    const float* x  = (const float*)d_in[0];
    const float* en = (const float*)d_in[1];
    const float* w0 = (const float*)d_in[2];
    const float* b0 = (const float*)d_in[3];
    const float* w1 = (const float*)d_in[4];
    const float* b1 = (const float*)d_in[5];
    const float* w2 = (const float*)d_in[6];
    const float* b2 = (const float*)d_in[7];
    float* out = (float*)d_out;

    const int N = in_sizes[0] / 2;      // 2^20 points
    const int nTiles = N / 16;          // 65536
    const int nGroups = nTiles / 4;     // 16384 (4 waves/block)

    const size_t tabBytes = (size_t)TSIZE * 8 * 2;               // 2 MB
    const size_t wsNeeded = tabBytes + (size_t)NDALL * 4;        // ~2.64 MB
    if (ws_size >= wsNeeded) {
        uint16_t* tab8  = (uint16_t*)d_ws;
        uint32_t* dpair = (uint32_t*)((char*)d_ws + tabBytes);
        const int preBlocks = 512 + (NDALL + 255) / 256;         // 1046
        prepass_all<<<preBlocks, 256, 0, stream>>>((const float2*)en, tab8, dpair);
        int blocks = 2048;
        if (blocks > nGroups) blocks = nGroups;
        fused_hash_mlp<<<blocks, 256, 0, stream>>>(x, tab8, dpair,
                                                   w0, b0, w1, b1, w2, b2, out, nGroups);
    } else {
        int blocks = 2048;
        if (blocks > nGroups) blocks = nGroups;
        fused_hash_mlp_fp32<<<blocks, 256, 0, stream>>>(x, en, w0, b0, w1, b1, w2, b2, out, nGroups);
    }
}

// Round 4
// 198.940 us; speedup vs baseline: 1.1406x; 1.0846x over previous
//
#include <hip/hip_runtime.h>
#include <stdint.h>

typedef __bf16 bf16_t;
typedef bf16_t bf16x8 __attribute__((ext_vector_type(8)));
typedef float  f32x4  __attribute__((ext_vector_type(4)));
typedef float  f32x2v __attribute__((ext_vector_type(2)));

static constexpr uint32_t PRIME = 2654435761u;
static constexpr uint32_t HMASK = (1u << 17) - 1u;   // HASHMAP_SIZE - 1
static constexpr uint32_t TSIZE = 1u << 17;

// dense mini-grid geometry, levels 0..7 (scale_l = 16*1.5^l, W = ceil(scale)+1)
static constexpr int NLDS   = 5308;     // levels 0..3 (17^2+25^2+37^2+55^2)
static constexpr int NDALL  = 136642;   // + levels 4..7 (82^2+123^2+184^2+275^2)

// features stored as fp8-e4m3 pairs, pre-scaled by 2^13 (|f|<=1e-4 -> +-0.82).
// un-scale 2^-13 is folded into the layer-0 weight fragments.
static constexpr float FSCALE = 8192.0f;        // 2^13
static constexpr float WSCALE = 1.0f / 8192.0f; // 2^-13

__device__ __forceinline__ uint32_t fbits(float f) {
    union { float f; uint32_t u; } v; v.f = f; return v.u;
}
__device__ __forceinline__ float asfloat(uint32_t u) {
    union { uint32_t u; float f; } v; v.u = u; return v.f;
}

// ---- fp8 pair encode/decode (OCP e4m3fn). HW path on gfx950, manual fallback.
__device__ __forceinline__ uint32_t enc8(float v) {   // manual e4m3fn RNE
    const uint32_t s = (fbits(v) >> 24) & 0x80u;
    float m = fabsf(v) * 0x1p-120f;                   // map e4m3 grid onto fp32 bits
    uint32_t u = fbits(m);
    u += 0x7FFFFu + ((u >> 20) & 1u);                 // RNE at bit 20
    return s | ((u >> 20) & 0x7fu);
}
__device__ __forceinline__ uint32_t pack8(float a, float b) {
#if __has_builtin(__builtin_amdgcn_cvt_pk_fp8_f32)
    return (uint32_t)__builtin_amdgcn_cvt_pk_fp8_f32(a, b, 0, false) & 0xffffu;
#else
    return enc8(a) | (enc8(b) << 8);
#endif
}
// unpack the low 16-bit fp8-pair of a dword (word-select must be an immediate)
template <bool HI>
__device__ __forceinline__ float2 unpack8w(uint32_t u) {
#if __has_builtin(__builtin_amdgcn_cvt_pk_f32_fp8)
    f32x2v r = __builtin_amdgcn_cvt_pk_f32_fp8((int)u, HI);
    return make_float2(r.x, r.y);
#else
    const uint32_t w = HI ? (u >> 16) : (u & 0xffffu);
    const float f0 = asfloat(((w & 0x80u) << 24) | ((w & 0x7fu) << 20)) * 0x1p120f;
    const float f1 = asfloat(((w & 0x8000u) << 16) | ((w & 0x7f00u) << 12)) * 0x1p120f;
    return make_float2(f0, f1);
#endif
}

// ---- single fused prepass (R2-verified):
// blocks [0,512):  repack levels 8..15 of fp32 [T][L][F] -> fp8-pair ushorts,
//                  level-major [l-8][T] (2 MB), LDS-tiled transpose.
// blocks [512,..): dense mini-grids, levels 0..7 (267 KB, fp8-pair u16).
__global__ __launch_bounds__(256)
void prepass_all(const float2* __restrict__ src, uint16_t* __restrict__ tab8,
                 uint16_t* __restrict__ dense) {
    __shared__ uint16_t ldsT[8 * 257];      // [l8][t_local], +1 pad
    const int tid = threadIdx.x;
    if (blockIdx.x < 512) {
        const int t0 = blockIdx.x * 256;    // 512 blocks x 256 t-entries
#pragma unroll
        for (int k = 0; k < 8; ++k) {
            const int j = k * 256 + tid;    // (t_local, l8): l8 fastest
            const int tl = j >> 3, l8 = j & 7;
            const float2 f = src[((size_t)(t0 + tl) << 4) + 8 + l8];
            ldsT[l8 * 257 + tl] = (uint16_t)pack8(f.x * FSCALE, f.y * FSCALE);
        }
        __syncthreads();
#pragma unroll
        for (int k = 0; k < 8; ++k)
            tab8[((uint32_t)k << 17) + t0 + tid] = ldsT[k * 257 + tid];
    } else {
        const int i = (blockIdx.x - 512) * 256 + tid;
        if (i >= NDALL) return;
        int lvl, W, off;
        if      (i <   289) { lvl = 0; W =  17; off = 0;     }
        else if (i <   914) { lvl = 1; W =  25; off = 289;   }
        else if (i <  2283) { lvl = 2; W =  37; off = 914;   }
        else if (i <  5308) { lvl = 3; W =  55; off = 2283;  }
        else if (i < 12032) { lvl = 4; W =  82; off = 5308;  }
        else if (i < 27161) { lvl = 5; W = 123; off = 12032; }
        else if (i < 61017) { lvl = 6; W = 184; off = 27161; }
        else                { lvl = 7; W = 275; off = 61017; }
        const int li = i - off;
        const uint32_t iy = (uint32_t)(li / W), ix = (uint32_t)(li % W);
        const uint32_t h = (ix ^ (iy * PRIME)) & HMASK;
        const float2 f = src[h * 16 + lvl];
        dense[i] = (uint16_t)pack8(f.x * FSCALE, f.y * FSCALE);
    }
}

// R0 STRUCTURE RESTORED (best-known-good, 130us) + the two verified wins:
//  (1) XOR-swizzled stride-64 transpose tile (R2/R3: bank conflicts 5.5M->0)
//  (2) fused single prepass dispatch.
// One wave = one 16-point tile per iteration. q = lane>>4, n16 = lane&15.
// Lane (q,n16) computes levels 4q..4q+3 of point n16 -> exactly the
// mfma_f32_16x16x32_bf16 A-fragment. Quad-uniform gather routing: q==0 ->
// LDS dense (lv 0..3, 10.6 KB); q==1 -> global dense mini-grids (lv 4..7,
// 267 KB); q>=2 -> hashed fp8 table (lv 8..15, 2 MB). Working set 2.3 MB
// < 4 MiB per-XCD L2. Weights in registers; per-wave private transpose
// tiles -> no block barriers in the loop.
__global__ __launch_bounds__(256, 2)
void fused_hash_mlp(const float* __restrict__ xin,
                    const uint16_t* __restrict__ tab8,   // hashed lv8..15, fp8
                    const uint16_t* __restrict__ dense,  // dense lv0..7, fp8
                    const float* __restrict__ w0, const float* __restrict__ b0,
                    const float* __restrict__ w1, const float* __restrict__ b1,
                    const float* __restrict__ w2, const float* __restrict__ b2,
                    float* __restrict__ out,
                    int nGroups)
{
    __shared__ uint16_t ldsTab[NLDS];                    // 10616 B
    __shared__ __align__(16) bf16_t lds[4 * 16 * 64];    // 8192 B per-wave tiles

    const int tid  = threadIdx.x;
    const int wib  = tid >> 6;      // 0..3
    const int lane = tid & 63;
    const int q    = lane >> 4;
    const int n16  = lane & 15;
    const int m7   = n16 & 7;
    const int mb   = n16 >> 3;

    bf16_t* myLds = &lds[wib * (16 * 64)];

    // cooperative fill of the LDS dense cache (levels 0..3)
    for (int i = tid; i < NLDS; i += 256) ldsTab[i] = dense[i];

    // ---- weight B-fragments (fp32 -> bf16 once). Bw0 absorbs the 2^-13
    // feature un-scale (A carries feat*2^13).
    bf16x8 Bw0[4], Bw1[2][4], Bw2[2];
#pragma unroll
    for (int t = 0; t < 4; ++t)
#pragma unroll
        for (int j = 0; j < 8; ++j)
            Bw0[t][j] = (bf16_t)(w0[(q * 8 + j) * 64 + t * 16 + n16] * WSCALE);
#pragma unroll
    for (int c = 0; c < 2; ++c)
#pragma unroll
        for (int t = 0; t < 4; ++t)
#pragma unroll
            for (int j = 0; j < 8; ++j)
                Bw1[c][t][j] = (bf16_t)w1[(c * 32 + q * 8 + j) * 64 + t * 16 + n16];
#pragma unroll
    for (int c = 0; c < 2; ++c)
#pragma unroll
        for (int j = 0; j < 8; ++j)
            Bw2[c][j] = (n16 < 3) ? (bf16_t)w2[(c * 32 + q * 8 + j) * 3 + n16]
                                  : (bf16_t)0.0f;

    float bv0[4], bv1[4];
#pragma unroll
    for (int t = 0; t < 4; ++t) {
        bv0[t] = b0[t * 16 + n16];
        bv1[t] = b1[t * 16 + n16];
    }
    const float bv2 = (n16 < 3) ? b2[n16] : 0.0f;

    // scales for levels 4q..4q+3: 16*1.5^l = 3^l * 2^(4-l) is EXACT in fp32,
    // so pos/floor/hash bit-match the fp32 numpy reference.
    const float sb = 16.0f * ((q == 0) ? 1.0f :
                              (q == 1) ? 5.0625f :           // 1.5^4
                              (q == 2) ? 25.62890625f :      // 1.5^8
                                         129.746337890625f); // 1.5^12
    const float sc[4] = { sb, sb * 1.5f, sb * 2.25f, sb * 3.375f };

    // hashed sub-table base for q>=2: level 4q+lv -> [(q-2)*4 + lv] << 17
    const uint32_t l8base = ((uint32_t)((q >= 2 ? q - 2 : 0) * 4)) << 17;

    // ---- swizzled transpose-tile addressing (element units, bf16) ----
    // write (row=4q+r, col=16t+n16): idx = row*64 + ((blk ^ swz(row))<<3)+ (col&7)
    // verified on HW in R2/R3: conflicts 5.5M -> 0, bit-identical output.
    int wbase[4];
#pragma unroll
    for (int r = 0; r < 4; ++r)
        wbase[r] = (q * 4 + r) * 64 + m7 + ((mb ^ (r & 1)) << 3) + ((q & 1) << 5);
    const int rIdx0 = n16 * 64 + (( q      ^ m7) << 3);   // c=0
    const int rIdx1 = n16 * 64 + (((4 + q) ^ m7) << 3);   // c=1

    __syncthreads();   // ldsTab ready (only block-wide barrier)

    for (int g = blockIdx.x; g < nGroups; g += gridDim.x) {
        const int tile = g * 4 + wib;
        const int p = tile * 16 + n16;
        const float2 xy = ((const float2*)xin)[p];
        const float px = xy.x, py = xy.y;

        bf16x8 af;
#pragma unroll
        for (int lv = 0; lv < 4; ++lv) {
            const float posx = px * sc[lv], posy = py * sc[lv];
            const float fx = floorf(posx), fy = floorf(posy);
            const float frx = posx - fx,  fry = posy - fy;
            const uint32_t ix = (uint32_t)fx, iy = (uint32_t)fy;

            // dense geometry for this lv-slot (compile-time under unroll)
            const uint32_t Wl = (lv == 0) ? 17u  : (lv == 1) ? 25u
                              : (lv == 2) ? 37u  : 55u;
            const uint32_t Ol = (lv == 0) ? 0u   : (lv == 1) ? 289u
                              : (lv == 2) ? 914u : 2283u;
            const uint32_t Wg = (lv == 0) ? 82u    : (lv == 1) ? 123u
                              : (lv == 2) ? 184u   : 275u;
            const uint32_t Og = (lv == 0) ? 5308u  : (lv == 1) ? 12032u
                              : (lv == 2) ? 27161u : 61017u;

            uint32_t u00, u10, u01, u11;
            if (q == 0) {            // levels 0..3: LDS dense
                const uint32_t a = Ol + iy * Wl + ix;
                u00 = ldsTab[a];
                u10 = ldsTab[a + 1];
                u01 = ldsTab[a + Wl];
                u11 = ldsTab[a + Wl + 1];
            } else if (q == 1) {     // levels 4..7: global dense (L2-resident)
                const uint32_t a = Og + iy * Wg + ix;
                u00 = dense[a];
                u10 = dense[a + 1];
                u01 = dense[a + Wg];
                u11 = dense[a + Wg + 1];
            } else {                 // levels 8..15: hashed fp8 (L2-resident)
                const uint32_t hy0 = iy * PRIME, hy1 = hy0 + PRIME;
                const uint32_t i00 = ( ix       ^ hy0) & HMASK;
                const uint32_t i10 = ((ix + 1u) ^ hy0) & HMASK;
                const uint32_t i01 = ( ix       ^ hy1) & HMASK;
                const uint32_t i11 = ((ix + 1u) ^ hy1) & HMASK;
                const uint32_t base = l8base + ((uint32_t)lv << 17);
                u00 = tab8[base + i00];
                u10 = tab8[base + i10];
                u01 = tab8[base + i01];
                u11 = tab8[base + i11];
            }

            const float2 e00 = unpack8w<false>(u00);
            const float2 e10 = unpack8w<false>(u10);
            const float2 e01 = unpack8w<false>(u01);
            const float2 e11 = unpack8w<false>(u11);
            const float wx1 = frx, wx0 = 1.0f - frx, wy1 = fry, wy0 = 1.0f - fry;
            const float w00 = wx0 * wy0, w10 = wx1 * wy0, w01 = wx0 * wy1, w11 = wx1 * wy1;
            // bilerp in the scaled (x2^13) domain; Bw0 un-scales.
            const float f0 = w00 * e00.x + w10 * e10.x + w01 * e01.x + w11 * e11.x;
            const float f1 = w00 * e00.y + w10 * e10.y + w01 * e01.y + w11 * e11.y;
            af[2 * lv]     = (bf16_t)f0;
            af[2 * lv + 1] = (bf16_t)f1;
        }

        // ---- layer 0: [16x32] @ [32x64] + b0, relu ----
        f32x4 c0[4];
#pragma unroll
        for (int t = 0; t < 4; ++t) {
            f32x4 cc = { bv0[t], bv0[t], bv0[t], bv0[t] };
            c0[t] = __builtin_amdgcn_mfma_f32_16x16x32_bf16(af, Bw0[t], cc, 0, 0, 0);
        }

        // C-layout -> A-layout via per-wave private swizzled LDS tile
#pragma unroll
        for (int t = 0; t < 4; ++t)
#pragma unroll
            for (int r = 0; r < 4; ++r) {
                const int idx = ((t < 2) ? wbase[r] : (wbase[r] ^ 32))
                              + ((((t & 1) ^ ((r >> 1) & 1))) << 4);
                myLds[idx] = (bf16_t)fmaxf(c0[t][r], 0.0f);
            }
        bf16x8 A1[2];
        A1[0] = *(const bf16x8*)&myLds[rIdx0];
        A1[1] = *(const bf16x8*)&myLds[rIdx1];

        // ---- layer 1: [16x64] @ [64x64] + b1, relu ----
        f32x4 c1[4];
#pragma unroll
        for (int t = 0; t < 4; ++t) {
            f32x4 cc = { bv1[t], bv1[t], bv1[t], bv1[t] };
            cc    = __builtin_amdgcn_mfma_f32_16x16x32_bf16(A1[0], Bw1[0][t], cc, 0, 0, 0);
            c1[t] = __builtin_amdgcn_mfma_f32_16x16x32_bf16(A1[1], Bw1[1][t], cc, 0, 0, 0);
        }

#pragma unroll
        for (int t = 0; t < 4; ++t)
#pragma unroll
            for (int r = 0; r < 4; ++r) {
                const int idx = ((t < 2) ? wbase[r] : (wbase[r] ^ 32))
                              + ((((t & 1) ^ ((r >> 1) & 1))) << 4);
                myLds[idx] = (bf16_t)fmaxf(c1[t][r], 0.0f);
            }
        bf16x8 A2[2];
        A2[0] = *(const bf16x8*)&myLds[rIdx0];
        A2[1] = *(const bf16x8*)&myLds[rIdx1];

        // ---- layer 2: [16x64] @ [64x3 padded to 16] + b2 (no relu) ----
        f32x4 co = { bv2, bv2, bv2, bv2 };
        co = __builtin_amdgcn_mfma_f32_16x16x32_bf16(A2[0], Bw2[0], co, 0, 0, 0);
        co = __builtin_amdgcn_mfma_f32_16x16x32_bf16(A2[1], Bw2[1], co, 0, 0, 0);

        if (n16 < 3) {
#pragma unroll
            for (int r = 0; r < 4; ++r)
                out[(size_t)(tile * 16 + q * 4 + r) * 3 + n16] = co[r];
        }
    }
}

// ---- fallback (known-good): direct fp32 gather, used only if ws too small
__global__ __launch_bounds__(256)
void fused_hash_mlp_fp32(const float* __restrict__ xin,
                         const float* __restrict__ enc,
                         const float* __restrict__ w0, const float* __restrict__ b0,
                         const float* __restrict__ w1, const float* __restrict__ b1,
                         const float* __restrict__ w2, const float* __restrict__ b2,
                         float* __restrict__ out,
                         int nGroups)
{
    __shared__ __align__(16) bf16_t lds[4 * 16 * 80];
    const int tid  = threadIdx.x;
    const int wib  = tid >> 6;
    const int lane = tid & 63;
    const int q    = lane >> 4;
    const int n16  = lane & 15;
    bf16_t* myLds = &lds[wib * (16 * 80)];

    bf16x8 Bw0[4], Bw1[2][4], Bw2[2];
#pragma unroll
    for (int t = 0; t < 4; ++t)
#pragma unroll
        for (int j = 0; j < 8; ++j)
            Bw0[t][j] = (bf16_t)w0[(q * 8 + j) * 64 + t * 16 + n16];
#pragma unroll
    for (int c = 0; c < 2; ++c)
#pragma unroll
        for (int t = 0; t < 4; ++t)
#pragma unroll
            for (int j = 0; j < 8; ++j)
                Bw1[c][t][j] = (bf16_t)w1[(c * 32 + q * 8 + j) * 64 + t * 16 + n16];
#pragma unroll
    for (int c = 0; c < 2; ++c)
#pragma unroll
        for (int j = 0; j < 8; ++j)
            Bw2[c][j] = (n16 < 3) ? (bf16_t)w2[(c * 32 + q * 8 + j) * 3 + n16]
                                  : (bf16_t)0.0f;

    float bv0[4], bv1[4];
#pragma unroll
    for (int t = 0; t < 4; ++t) { bv0[t] = b0[t * 16 + n16]; bv1[t] = b1[t * 16 + n16]; }
    const float bv2 = (n16 < 3) ? b2[n16] : 0.0f;

    const float sb = 16.0f * ((q == 0) ? 1.0f : (q == 1) ? 5.0625f :
                              (q == 2) ? 25.62890625f : 129.746337890625f);
    const float sc[4] = { sb, sb * 1.5f, sb * 2.25f, sb * 3.375f };
    const char* encB = (const char*)enc;
    const uint32_t lvBase = (uint32_t)q * 32u;

    for (int g = blockIdx.x; g < nGroups; g += gridDim.x) {
        const int tile = g * 4 + wib;
        const int p = tile * 16 + n16;
        const float2 xy = ((const float2*)xin)[p];
        const float px = xy.x, py = xy.y;

        bf16x8 af;
#pragma unroll
        for (int lv = 0; lv < 4; ++lv) {
            const float posx = px * sc[lv], posy = py * sc[lv];
            const float fx = floorf(posx), fy = floorf(posy);
            const float frx = posx - fx,  fry = posy - fy;
            const uint32_t ix = (uint32_t)fx, iy = (uint32_t)fy;
            const uint32_t hy0 = iy * PRIME, hy1 = hy0 + PRIME;
            const uint32_t i00 = ( ix       ^ hy0) & HMASK;
            const uint32_t i10 = ((ix + 1u) ^ hy0) & HMASK;
            const uint32_t i01 = ( ix       ^ hy1) & HMASK;
            const uint32_t i11 = ((ix + 1u) ^ hy1) & HMASK;
            const uint32_t off = lvBase + (uint32_t)lv * 8u;
            const float2 e00 = *(const float2*)(encB + (i00 * 128u + off));
            const float2 e10 = *(const float2*)(encB + (i10 * 128u + off));
            const float2 e01 = *(const float2*)(encB + (i01 * 128u + off));
            const float2 e11 = *(const float2*)(encB + (i11 * 128u + off));
            const float wx1 = frx, wx0 = 1.0f - frx, wy1 = fry, wy0 = 1.0f - fry;
            const float w00 = wx0 * wy0, w10 = wx1 * wy0, w01 = wx0 * wy1, w11 = wx1 * wy1;
            af[2 * lv]     = (bf16_t)(w00 * e00.x + w10 * e10.x + w01 * e01.x + w11 * e11.x);
            af[2 * lv + 1] = (bf16_t)(w00 * e00.y + w10 * e10.y + w01 * e01.y + w11 * e11.y);
        }

        f32x4 c0[4];
#pragma unroll
        for (int t = 0; t < 4; ++t) {
            f32x4 cc = { bv0[t], bv0[t], bv0[t], bv0[t] };
            c0[t] = __builtin_amdgcn_mfma_f32_16x16x32_bf16(af, Bw0[t], cc, 0, 0, 0);
        }
        __syncthreads();
#pragma unroll
        for (int t = 0; t < 4; ++t)
#pragma unroll
            for (int r = 0; r < 4; ++r)
                myLds[(q * 4 + r) * 80 + t * 16 + n16] = (bf16_t)fmaxf(c0[t][r], 0.0f);
        __syncthreads();
        bf16x8 A1[2];
#pragma unroll
        for (int c = 0; c < 2; ++c)
            A1[c] = *(const bf16x8*)&myLds[n16 * 80 + c * 32 + q * 8];

        f32x4 c1[4];
#pragma unroll
        for (int t = 0; t < 4; ++t) {
            f32x4 cc = { bv1[t], bv1[t], bv1[t], bv1[t] };
            cc    = __builtin_amdgcn_mfma_f32_16x16x32_bf16(A1[0], Bw1[0][t], cc, 0, 0, 0);
            c1[t] = __builtin_amdgcn_mfma_f32_16x16x32_bf16(A1[1], Bw1[1][t], cc, 0, 0, 0);
        }
        __syncthreads();
#pragma unroll
        for (int t = 0; t < 4; ++t)
#pragma unroll
            for (int r = 0; r < 4; ++r)
                myLds[(q * 4 + r) * 80 + t * 16 + n16] = (bf16_t)fmaxf(c1[t][r], 0.0f);
        __syncthreads();
        bf16x8 A2[2];
#pragma unroll
        for (int c = 0; c < 2; ++c)
            A2[c] = *(const bf16x8*)&myLds[n16 * 80 + c * 32 + q * 8];

        f32x4 co = { bv2, bv2, bv2, bv2 };
        co = __builtin_amdgcn_mfma_f32_16x16x32_bf16(A2[0], Bw2[0], co, 0, 0, 0);
        co = __builtin_amdgcn_mfma_f32_16x16x32_bf16(A2[1], Bw2[1], co, 0, 0, 0);
        if (n16 < 3) {
#pragma unroll
            for (int r = 0; r < 4; ++r)
                out[(size_t)(tile * 16 + q * 4 + r) * 3 + n16] = co[r];
        }
    }
}

extern "C" void kernel_launch(void* const* d_in, const int* in_sizes, int n_in,
                              void* d_out, int out_size, void* d_ws, size_t ws_size,
                              hipStream_t stream) {
    const float* x  = (const float*)d_in[0];
    const float* en = (const float*)d_in[1];
    const float* w0 = (const float*)d_in[2];
    const float* b0 = (const float*)d_in[3];
    const float* w1 = (const float*)d_in[4];
    const float* b1 = (const float*)d_in[5];
    const float* w2 = (const float*)d_in[6];
    const float* b2 = (const float*)d_in[7];
    float* out = (float*)d_out;

    const int N = in_sizes[0] / 2;      // 2^20 points
    const int nTiles = N / 16;          // 65536
    const int nGroups = nTiles / 4;     // 16384 (4 waves/block)

    const size_t wsNeeded = ((size_t)TSIZE * 8 + NDALL) * 2;   // ~2.37 MB
    if (ws_size >= wsNeeded) {
        uint16_t* tab8  = (uint16_t*)d_ws;
        uint16_t* dense = tab8 + ((size_t)TSIZE * 8);
        const int preBlocks = 512 + (NDALL + 255) / 256;       // 1046
        prepass_all<<<preBlocks, 256, 0, stream>>>((const float2*)en, tab8, dense);
        int blocks = 2048;
        if (blocks > nGroups) blocks = nGroups;
        fused_hash_mlp<<<blocks, 256, 0, stream>>>(x, tab8, dense,
                                                   w0, b0, w1, b1, w2, b2, out, nGroups);
    } else {
        int blocks = 2048;
        if (blocks > nGroups) blocks = nGroups;
        fused_hash_mlp_fp32<<<blocks, 256, 0, stream>>>(x, en, w0, b0, w1, b1, w2, b2, out, nGroups);
    }
}